// Round 3
// baseline (383.245 us; speedup 1.0000x reference)
//
#include <hip/hip_runtime.h>
#include <hip/hip_bf16.h>
#include <math.h>

// Problem constants
#define C_DIM 256      // channels
#define SPAT 4096      // h*w = 64*64
#define HEADS_N 8
#define DHEAD 64
#define MEMTOK 4
#define TTOK 4100      // MEMTOK + SPAT
#define TTOKP 4160     // padded to 65 tiles of 64
#define HID 512        // HEADS_N * DHEAD
#define PITCHP 68      // P LDS pitch (bf16 elems): 34 dwords -> 2-bank shift/row

typedef __bf16 bf16x8 __attribute__((ext_vector_type(8)));
typedef unsigned short u16x8 __attribute__((ext_vector_type(8)));
typedef float f32x4 __attribute__((ext_vector_type(4)));

static __device__ inline unsigned short f2bf(float f) {  // RNE f32->bf16
    unsigned int u = __float_as_uint(f);
    u += 0x7fffu + ((u >> 16) & 1u);
    return (unsigned short)(u >> 16);
}

static __device__ inline bf16x8 ldb8(const unsigned short* p) {
    union { u16x8 u; bf16x8 b; } t;
    t.u = *(const u16x8*)p;
    return t.b;
}

// ---------------------------------------------------------------------------
// Kernel 1: inverse RMS norm per pixel: invn[p] = rsqrt(sum_c x^2) * 16
// ---------------------------------------------------------------------------
__global__ __launch_bounds__(256) void rms_inv(const float* __restrict__ x,
                                               float* __restrict__ invn) {
    int p = blockIdx.x * 256 + threadIdx.x;  // 16 blocks
    float ss = 0.f;
    for (int c = 0; c < C_DIM; ++c) {
        float v = x[c * SPAT + p];
        ss += v * v;
    }
    invn[p] = rsqrtf(ss) * 16.0f;
}

// ---------------------------------------------------------------------------
// Kernel 2: mem_kv copy (bf16) + zero-fill pad rows/cols (ws is re-poisoned!)
// kb: [h][TTOKP][64] bf16, rows 0..3 = mem k, rows 4100..4159 zero
// vtb: [h][64][TTOKP] bf16 (transposed), cols 0..3 = mem v, cols 4100.. zero
// ---------------------------------------------------------------------------
__global__ __launch_bounds__(256) void fixup_kernel(const float* __restrict__ mem,
                                                    unsigned short* __restrict__ kb,
                                                    unsigned short* __restrict__ vtb) {
    int i = blockIdx.x * 256 + threadIdx.x;
    if (i < 4096) {
        int d = i & 63, m = (i >> 6) & 3, h = (i >> 8) & 7, s = (i >> 11) & 1;
        unsigned short val = f2bf(mem[i]);
        if (s == 0) kb[(size_t)h * TTOKP * 64 + m * 64 + d] = val;
        else        vtb[((size_t)h * 64 + d) * TTOKP + m] = val;
    } else {
        int z = i - 4096;              // 0..61439
        if (z < 30720) {               // kb pad rows
            int h = z / 3840, r = z % 3840;
            int row = TTOK + r / 64, d = r % 64;
            kb[(size_t)h * TTOKP * 64 + row * 64 + d] = 0;
        } else {                       // vtb pad cols
            z -= 30720;
            int h = z / 3840, r = z % 3840;
            int d = r / 60, tcol = TTOK + r % 60;
            vtb[((size_t)h * 64 + d) * TTOKP + tcol] = 0;
        }
    }
}

// ---------------------------------------------------------------------------
// Kernel 3: QKV GEMM (fp32 compute, bf16 outputs), RMSNorm fused into staging.
// q gets folded scale 0.125*log2(e) (softmax scale + exp2 domain).
// q: [h][4096][64]; k: [h][TTOKP][64] (rows 4..4099); v: [h][64][TTOKP] transposed.
// ---------------------------------------------------------------------------
__global__ __launch_bounds__(256) void qkv_gemm(const float* __restrict__ w,
                                                const float* __restrict__ x,
                                                const float* __restrict__ invn,
                                                const float* __restrict__ gamma,
                                                unsigned short* __restrict__ qb,
                                                unsigned short* __restrict__ kb,
                                                unsigned short* __restrict__ vtb) {
    int tile_p = blockIdx.x;            // 0..63
    int tile_o = blockIdx.y;            // 0..23
    int o0 = tile_o * 64, p0 = tile_p * 64;
    __shared__ float smem[2 * 16 * 68];
    float (*wt)[68] = (float(*)[68])smem;            // [lc][lo]
    float (*xt)[68] = (float(*)[68])(smem + 16 * 68); // [lc][lp]
    int t = threadIdx.x;
    int tx = t & 15, ty = t >> 4;
    float acc[4][4];
#pragma unroll
    for (int i = 0; i < 4; ++i)
#pragma unroll
        for (int j = 0; j < 4; ++j) acc[i][j] = 0.f;

    for (int c0 = 0; c0 < C_DIM; c0 += 16) {
        __syncthreads();
        {   // w tile (64 o x 16 c), transposed
            int lo = t >> 2, lc4 = (t & 3) * 4;
            float4 wv = *(const float4*)&w[(size_t)(o0 + lo) * C_DIM + c0 + lc4];
            wt[lc4 + 0][lo] = wv.x; wt[lc4 + 1][lo] = wv.y;
            wt[lc4 + 2][lo] = wv.z; wt[lc4 + 3][lo] = wv.w;
        }
        {   // x tile (16 c x 64 p), normalized on the fly
            int lc = t >> 4, lp4 = (t & 15) * 4;
            float4 xv = *(const float4*)&x[(size_t)(c0 + lc) * SPAT + p0 + lp4];
            float4 iv = *(const float4*)&invn[p0 + lp4];
            float g1 = gamma[c0 + lc] + 1.0f;
            xt[lc][lp4 + 0] = xv.x * iv.x * g1;
            xt[lc][lp4 + 1] = xv.y * iv.y * g1;
            xt[lc][lp4 + 2] = xv.z * iv.z * g1;
            xt[lc][lp4 + 3] = xv.w * iv.w * g1;
        }
        __syncthreads();
#pragma unroll
        for (int lc = 0; lc < 16; ++lc) {
            float4 a4 = *(float4*)&wt[lc][tx * 4];
            float4 b4 = *(float4*)&xt[lc][ty * 4];
            float av[4] = {a4.x, a4.y, a4.z, a4.w};
            float bv[4] = {b4.x, b4.y, b4.z, b4.w};
#pragma unroll
            for (int i = 0; i < 4; ++i)
#pragma unroll
                for (int j = 0; j < 4; ++j) acc[i][j] += av[i] * bv[j];
        }
    }
    int sec = tile_o >> 3, h = tile_o & 7;
    if (sec == 0) {
        const float QSC = 0.125f * 1.4426950408889634f;
        unsigned short* dst = qb + (size_t)h * SPAT * 64;
#pragma unroll
        for (int j = 0; j < 4; ++j) {
            int p = p0 + ty * 4 + j;
            ushort4 val = {f2bf(acc[0][j] * QSC), f2bf(acc[1][j] * QSC),
                           f2bf(acc[2][j] * QSC), f2bf(acc[3][j] * QSC)};
            *(ushort4*)&dst[(size_t)p * 64 + tx * 4] = val;
        }
    } else if (sec == 1) {
        unsigned short* dst = kb + (size_t)h * TTOKP * 64;
#pragma unroll
        for (int j = 0; j < 4; ++j) {
            int tt = MEMTOK + p0 + ty * 4 + j;
            ushort4 val = {f2bf(acc[0][j]), f2bf(acc[1][j]),
                           f2bf(acc[2][j]), f2bf(acc[3][j])};
            *(ushort4*)&dst[(size_t)tt * 64 + tx * 4] = val;
        }
    } else {  // v transposed: [d][t] — LDS transpose for coalesced stores
        unsigned short* vst = (unsigned short*)smem;   // 64 x 68 bf16 (8704 B)
        __syncthreads();
#pragma unroll
        for (int i = 0; i < 4; ++i)
#pragma unroll
            for (int j = 0; j < 4; ++j)
                vst[(tx * 4 + i) * 68 + ty * 4 + j] = f2bf(acc[i][j]);
        __syncthreads();
        unsigned short* dst = vtb + (size_t)h * 64 * TTOKP;
        int row = t >> 2;            // d 0..63
        int off = (t & 3) * 16;      // 0,16,32,48
        size_t gbase = (size_t)row * TTOKP + MEMTOK + p0 + off;
#pragma unroll
        for (int q = 0; q < 4; ++q)  // 8B stores (addr only 8B-aligned)
            *(ushort4*)&dst[gbase + q * 4] = *(ushort4*)&vst[row * 68 + off + q * 4];
    }
}

// ---------------------------------------------------------------------------
// Kernel 4: flash attention, barrier-free. Each wave: 16 q-rows x one K-chunk.
// All MFMA operands loaded straight from global (K/V are L2/L3-resident);
// only P's C->A layout transform round-trips a per-wave LDS region.
// Split-K x2: chunk0 = tiles 0..32, chunk1 = tiles 33..64 (incl. 4-key tail).
// Outputs: undivided O partials + (m,l) per row for the merge pass.
// ---------------------------------------------------------------------------
__global__ __launch_bounds__(256) void attn_flash(const unsigned short* __restrict__ qb,
                                                  const unsigned short* __restrict__ kb,
                                                  const unsigned short* __restrict__ vtb,
                                                  float* __restrict__ Op,
                                                  float2* __restrict__ Ml) {
    const int h = blockIdx.y;
    const int split = blockIdx.z;
    const int p0 = blockIdx.x * 64;
    const int ts = split ? 33 : 0;
    const int te = split ? 65 : 33;

    __shared__ unsigned short Ps[4 * 16 * PITCHP];

    const int t = threadIdx.x;
    const int w = t >> 6;
    const int lane = t & 63;
    const int col16 = lane & 15;
    const int quad = lane >> 4;

    const unsigned short* qh = qb + (size_t)h * SPAT * 64;
    const unsigned short* kh = kb + (size_t)h * TTOKP * 64;
    const unsigned short* vh = vtb + (size_t)h * 64 * TTOKP;

    // Q fragments (A-layout): row = w*16+col16, k = quad*8..+7 (and +32)
    const unsigned short* qr = &qh[(size_t)(p0 + w * 16 + col16) * 64 + quad * 8];
    bf16x8 aq0 = ldb8(qr);
    bf16x8 aq1 = ldb8(qr + 32);

    f32x4 Oa[4];
    float m_i[4], l_i[4];
#pragma unroll
    for (int r = 0; r < 4; ++r) { m_i[r] = -1e30f; l_i[r] = 0.f; }
#pragma unroll
    for (int nt = 0; nt < 4; ++nt) Oa[nt] = (f32x4){0.f, 0.f, 0.f, 0.f};

    unsigned short* pw = &Ps[w * 16 * PITCHP];

    for (int tile = ts; tile < te; ++tile) {
        const int tb = tile << 6;
        // K fragments (B-layout): n = nt*16+col16 (key), k = quad*8+j (dim)
        bf16x8 bk0[4], bk1[4];
#pragma unroll
        for (int nt = 0; nt < 4; ++nt) {
            const unsigned short* kr = &kh[(size_t)(tb + nt * 16 + col16) * 64 + quad * 8];
            bk0[nt] = ldb8(kr);
            bk1[nt] = ldb8(kr + 32);
        }
        f32x4 sv[4];
#pragma unroll
        for (int nt = 0; nt < 4; ++nt) sv[nt] = (f32x4){0.f, 0.f, 0.f, 0.f};
#pragma unroll
        for (int nt = 0; nt < 4; ++nt) {
            sv[nt] = __builtin_amdgcn_mfma_f32_16x16x32_bf16(aq0, bk0[nt], sv[nt], 0, 0, 0);
            sv[nt] = __builtin_amdgcn_mfma_f32_16x16x32_bf16(aq1, bk1[nt], sv[nt], 0, 0, 0);
        }

        // V fragments (B-layout for PV): n = nt*16+col16 (dim), k = quad*8+j (key)
        // issued now so they are in flight during softmax
        bf16x8 bv0[4], bv1[4];
#pragma unroll
        for (int nt = 0; nt < 4; ++nt) {
            const unsigned short* vr = &vh[(size_t)(nt * 16 + col16) * TTOKP + tb + quad * 8];
            bv0[nt] = ldb8(vr);
            bv1[nt] = ldb8(vr + 32);
        }

        if (tile == 64) {   // only keys 4096..4099 valid in the tail tile
#pragma unroll
            for (int nt = 0; nt < 4; ++nt)
#pragma unroll
                for (int r = 0; r < 4; ++r)
                    if (nt * 16 + col16 >= TTOK - 4096) sv[nt][r] = -1e30f;
        }

        // online softmax (exp2 domain); row = quad*4+r
        float alpha[4];
#pragma unroll
        for (int r = 0; r < 4; ++r) {
            float rm = fmaxf(fmaxf(sv[0][r], sv[1][r]), fmaxf(sv[2][r], sv[3][r]));
            rm = fmaxf(rm, __shfl_xor(rm, 1, 64));
            rm = fmaxf(rm, __shfl_xor(rm, 2, 64));
            rm = fmaxf(rm, __shfl_xor(rm, 4, 64));
            rm = fmaxf(rm, __shfl_xor(rm, 8, 64));
            float mn = fmaxf(m_i[r], rm);
            alpha[r] = __builtin_amdgcn_exp2f(m_i[r] - mn);
            m_i[r] = mn;
            float rs = 0.f;
#pragma unroll
            for (int nt = 0; nt < 4; ++nt) {
                float pv = __builtin_amdgcn_exp2f(sv[nt][r] - mn);
                sv[nt][r] = pv;
                rs += pv;
            }
            rs += __shfl_xor(rs, 1, 64);
            rs += __shfl_xor(rs, 2, 64);
            rs += __shfl_xor(rs, 4, 64);
            rs += __shfl_xor(rs, 8, 64);
            l_i[r] = l_i[r] * alpha[r] + rs;
        }
#pragma unroll
        for (int nt = 0; nt < 4; ++nt) {
            Oa[nt][0] *= alpha[0]; Oa[nt][1] *= alpha[1];
            Oa[nt][2] *= alpha[2]; Oa[nt][3] *= alpha[3];
        }

        // P: C-layout -> per-wave LDS -> A-layout (no barrier: wave-private)
#pragma unroll
        for (int nt = 0; nt < 4; ++nt)
#pragma unroll
            for (int r = 0; r < 4; ++r)
                pw[(quad * 4 + r) * PITCHP + nt * 16 + col16] = f2bf(sv[nt][r]);

        bf16x8 pa0 = ldb8(&pw[col16 * PITCHP + quad * 8]);
        bf16x8 pa1 = ldb8(&pw[col16 * PITCHP + 32 + quad * 8]);

#pragma unroll
        for (int nt = 0; nt < 4; ++nt) {
            Oa[nt] = __builtin_amdgcn_mfma_f32_16x16x32_bf16(pa0, bv0[nt], Oa[nt], 0, 0, 0);
            Oa[nt] = __builtin_amdgcn_mfma_f32_16x16x32_bf16(pa1, bv1[nt], Oa[nt], 0, 0, 0);
        }
    }

    // epilogue: store undivided partials + (m,l)
    size_t rowbase = ((size_t)(split * HEADS_N + h) * SPAT + p0 + w * 16);
#pragma unroll
    for (int nt = 0; nt < 4; ++nt)
#pragma unroll
        for (int r = 0; r < 4; ++r)
            Op[(rowbase + quad * 4 + r) * 64 + nt * 16 + col16] = Oa[nt][r];
    if (col16 == 0) {
#pragma unroll
        for (int r = 0; r < 4; ++r)
            Ml[rowbase + quad * 4 + r] = make_float2(m_i[r], l_i[r]);
    }
}

// ---------------------------------------------------------------------------
// Kernel 5: merge split-K partials -> ob[h][p][d] (fp32)
// ---------------------------------------------------------------------------
__global__ __launch_bounds__(256) void merge_kernel(const float* __restrict__ Op,
                                                    const float2* __restrict__ Ml,
                                                    float* __restrict__ ob) {
    int g = blockIdx.x * 256 + threadIdx.x;   // float4 index, 0..524287
    int row = g >> 4;                          // h*4096+p
    float4 o0 = ((const float4*)Op)[g];
    float4 o1 = ((const float4*)(Op + (size_t)HEADS_N * SPAT * 64))[g];
    float2 ml0 = Ml[row];
    float2 ml1 = Ml[row + HEADS_N * SPAT];
    float m = fmaxf(ml0.x, ml1.x);
    float w0 = __builtin_amdgcn_exp2f(ml0.x - m);
    float w1 = __builtin_amdgcn_exp2f(ml1.x - m);
    float inv = 1.0f / (w0 * ml0.y + w1 * ml1.y);
    float a0 = w0 * inv, a1 = w1 * inv;
    float4 o;
    o.x = o0.x * a0 + o1.x * a1;
    o.y = o0.y * a0 + o1.y * a1;
    o.z = o0.z * a0 + o1.z * a1;
    o.w = o0.w * a0 + o1.w * a1;
    ((float4*)ob)[g] = o;
}

// ---------------------------------------------------------------------------
// Kernel 6: out projection (fp32): out[oc,p] = sum_{h,d} w_out[oc,h*64+d]*ob[h][p][d]
// ---------------------------------------------------------------------------
__global__ __launch_bounds__(256) void out_gemm(const float* __restrict__ w,
                                                const float* __restrict__ ob,
                                                float* __restrict__ out) {
    int p0 = blockIdx.x * 64;
    int o0 = blockIdx.y * 64;
    __shared__ float at[16][68];
    __shared__ float bt[16][68];
    int t = threadIdx.x;
    int tx = t & 15, ty = t >> 4;
    float acc[4][4];
#pragma unroll
    for (int i = 0; i < 4; ++i)
#pragma unroll
        for (int j = 0; j < 4; ++j) acc[i][j] = 0.f;

    for (int c0 = 0; c0 < HID; c0 += 16) {
        int hh = c0 >> 6;
        int d0 = c0 & 63;
        __syncthreads();
        {
            int lo = t >> 2, lc4 = (t & 3) * 4;
            float4 wv = *(const float4*)&w[(size_t)(o0 + lo) * HID + c0 + lc4];
            at[lc4 + 0][lo] = wv.x; at[lc4 + 1][lo] = wv.y;
            at[lc4 + 2][lo] = wv.z; at[lc4 + 3][lo] = wv.w;
        }
        {
            int lp = t >> 2, ld4 = (t & 3) * 4;
            float4 bv = *(const float4*)&ob[(size_t)hh * SPAT * 64 + (size_t)(p0 + lp) * 64 + d0 + ld4];
            bt[ld4 + 0][lp] = bv.x; bt[ld4 + 1][lp] = bv.y;
            bt[ld4 + 2][lp] = bv.z; bt[ld4 + 3][lp] = bv.w;
        }
        __syncthreads();
#pragma unroll
        for (int lc = 0; lc < 16; ++lc) {
            float4 a4 = *(float4*)&at[lc][tx * 4];
            float4 b4 = *(float4*)&bt[lc][ty * 4];
            float av[4] = {a4.x, a4.y, a4.z, a4.w};
            float bv[4] = {b4.x, b4.y, b4.z, b4.w};
#pragma unroll
            for (int i = 0; i < 4; ++i)
#pragma unroll
                for (int j = 0; j < 4; ++j) acc[i][j] += av[i] * bv[j];
        }
    }
#pragma unroll
    for (int i = 0; i < 4; ++i) {
        float4 val = {acc[i][0], acc[i][1], acc[i][2], acc[i][3]};
        *(float4*)&out[(size_t)(o0 + tx * 4 + i) * SPAT + p0 + ty * 4] = val;
    }
}

// ---------------------------------------------------------------------------
// Launch
// ---------------------------------------------------------------------------
extern "C" void kernel_launch(void* const* d_in, const int* in_sizes, int n_in,
                              void* d_out, int out_size, void* d_ws, size_t ws_size,
                              hipStream_t stream) {
    const float* x      = (const float*)d_in[0];
    const float* gamma  = (const float*)d_in[1];
    const float* mem_kv = (const float*)d_in[2];
    const float* w_qkv  = (const float*)d_in[3];
    const float* w_out  = (const float*)d_in[4];
    float* out = (float*)d_out;

    // workspace: invn | qb(bf16) | kb(bf16) | vtb(bf16) | ob(f32) | Op(f32 x2) | Ml  ~37.8 MB
    float* invn = (float*)d_ws;
    unsigned short* qb  = (unsigned short*)(invn + SPAT);
    unsigned short* kb  = qb + (size_t)HEADS_N * SPAT * DHEAD;
    unsigned short* vtb = kb + (size_t)HEADS_N * TTOKP * DHEAD;
    float* ob = (float*)(vtb + (size_t)HEADS_N * DHEAD * TTOKP);
    float* Op = ob + (size_t)HEADS_N * SPAT * DHEAD;
    float2* Ml = (float2*)(Op + (size_t)2 * HEADS_N * SPAT * DHEAD);

    rms_inv<<<dim3(16), 256, 0, stream>>>(x, invn);
    fixup_kernel<<<dim3(256), 256, 0, stream>>>(mem_kv, kb, vtb);
    qkv_gemm<<<dim3(64, 24), 256, 0, stream>>>(w_qkv, x, invn, gamma, qb, kb, vtb);
    attn_flash<<<dim3(64, HEADS_N, 2), 256, 0, stream>>>(qb, kb, vtb, Op, Ml);
    merge_kernel<<<dim3(2048), 256, 0, stream>>>(Op, Ml, ob);
    out_gemm<<<dim3(64, 4), 256, 0, stream>>>(w_out, ob, out);
}

// Round 6
// 308.216 us; speedup vs baseline: 1.2434x; 1.2434x over previous
//
#include <hip/hip_runtime.h>
#include <hip/hip_bf16.h>

#define C_DIM 256
#define SPAT 4096
#define HEADS_N 8
#define DHEAD 64
#define MEMTOK 4
#define TTOK 4100
#define TTOKP 4160
#define HID 512
#define QSCALE (0.125f * 1.4426950408889634f)
#define PITCHP 68      // P LDS pitch (bf16 elems)

typedef __bf16 bf16x8 __attribute__((ext_vector_type(8)));
typedef unsigned short u16x8 __attribute__((ext_vector_type(8)));
typedef float f32x4 __attribute__((ext_vector_type(4)));

static __device__ inline unsigned short f2bf(float f) {  // RNE f32->bf16
    unsigned int u = __float_as_uint(f);
    u += 0x7fffu + ((u >> 16) & 1u);
    return (unsigned short)(u >> 16);
}
static __device__ inline bf16x8 ldb8(const unsigned short* p) {
    union { u16x8 u; bf16x8 b; } t;
    t.u = *(const u16x8*)p;
    return t.b;
}
#define AS1 __attribute__((address_space(1)))
#define AS3 __attribute__((address_space(3)))
static __device__ inline void gload_lds16(const unsigned short* g, unsigned short* l) {
    __builtin_amdgcn_global_load_lds((const AS1 unsigned int*)g, (AS3 unsigned int*)l, 16, 0, 0);
}

// ---------------------------------------------------------------------------
// rms_inv: invn[p] = rsqrt(sum_c x[c][p]^2) * 16
// ---------------------------------------------------------------------------
__global__ __launch_bounds__(256) void rms_inv(const float* __restrict__ x,
                                               float* __restrict__ invn) {
    int p0 = blockIdx.x * 64;
    int tp = threadIdx.x & 63, tg = threadIdx.x >> 6;
    float ss = 0.f;
    for (int c = tg * 64; c < tg * 64 + 64; ++c) {
        float v = x[c * SPAT + p0 + tp];
        ss += v * v;
    }
    __shared__ float red[4][64];
    red[tg][tp] = ss;
    __syncthreads();
    if (tg == 0)
        invn[p0 + tp] = rsqrtf(red[0][tp] + red[1][tp] + red[2][tp] + red[3][tp]) * 16.0f;
}

// ---------------------------------------------------------------------------
// fixup: mem_kv (bf16) + zero pads. kb[t][d]: rows 0..3 = mem k, 4100..4159 = 0.
// vtb[d][t]: cols 0..3 = mem v, cols 4100..4159 = 0.
// ---------------------------------------------------------------------------
__global__ __launch_bounds__(256) void fixup_kernel(const float* __restrict__ mem,
                                                    unsigned short* __restrict__ kb,
                                                    unsigned short* __restrict__ vtb) {
    int i = blockIdx.x * 256 + threadIdx.x;
    if (i < 4096) {
        int d = i & 63, m = (i >> 6) & 3, h = (i >> 8) & 7, s = (i >> 11) & 1;
        unsigned short val = f2bf(mem[i]);
        if (s == 0) kb[(size_t)h * TTOKP * 64 + m * 64 + d] = val;
        else        vtb[((size_t)h * 64 + d) * TTOKP + m] = val;
    } else {
        int z = i - 4096;
        if (z < 30720) {
            int h = z / 3840, r = z % 3840;
            kb[(size_t)h * TTOKP * 64 + (TTOK + r / 64) * 64 + (r % 64)] = 0;
        } else {
            z -= 30720;
            int h = z / 3840, r = z % 3840;
            vtb[((size_t)h * 64 + r / 60) * TTOKP + TTOK + r % 60] = 0;
        }
    }
}

// ---------------------------------------------------------------------------
// qkv_gemm (fp32 compute, bf16 outputs), RMSNorm fused into staging.
// q gets folded scale 0.125*log2e. q:[h][4096][64]; k:[h][TTOKP][64];
// v:[h][64][TTOKP] transposed (un-permuted).
// ---------------------------------------------------------------------------
__global__ __launch_bounds__(256) void qkv_gemm(const float* __restrict__ w,
                                                const float* __restrict__ x,
                                                const float* __restrict__ invn,
                                                const float* __restrict__ gamma,
                                                unsigned short* __restrict__ qb,
                                                unsigned short* __restrict__ kb,
                                                unsigned short* __restrict__ vtb) {
    int tile_p = blockIdx.x;            // 0..63
    int tile_o = blockIdx.y;            // 0..23
    int o0 = tile_o * 64, p0 = tile_p * 64;
    __shared__ float smem[2 * 16 * 68];
    float (*wt)[68] = (float(*)[68])smem;             // [lc][lo]
    float (*xt)[68] = (float(*)[68])(smem + 16 * 68); // [lc][lp]
    int t = threadIdx.x;
    int tx = t & 15, ty = t >> 4;
    float acc[4][4];
#pragma unroll
    for (int i = 0; i < 4; ++i)
#pragma unroll
        for (int j = 0; j < 4; ++j) acc[i][j] = 0.f;

    for (int c0 = 0; c0 < C_DIM; c0 += 16) {
        __syncthreads();
        {   // w tile (64 o x 16 c), transposed
            int lo = t >> 2, lc4 = (t & 3) * 4;
            float4 wv = *(const float4*)&w[(size_t)(o0 + lo) * C_DIM + c0 + lc4];
            wt[lc4 + 0][lo] = wv.x; wt[lc4 + 1][lo] = wv.y;
            wt[lc4 + 2][lo] = wv.z; wt[lc4 + 3][lo] = wv.w;
        }
        {   // x tile (16 c x 64 p), normalized on the fly
            int lc = t >> 4, lp4 = (t & 15) * 4;
            float4 xv = *(const float4*)&x[(size_t)(c0 + lc) * SPAT + p0 + lp4];
            float4 iv = *(const float4*)&invn[p0 + lp4];
            float g1 = gamma[c0 + lc] + 1.0f;
            xt[lc][lp4 + 0] = xv.x * iv.x * g1;
            xt[lc][lp4 + 1] = xv.y * iv.y * g1;
            xt[lc][lp4 + 2] = xv.z * iv.z * g1;
            xt[lc][lp4 + 3] = xv.w * iv.w * g1;
        }
        __syncthreads();
#pragma unroll
        for (int lc = 0; lc < 16; ++lc) {
            float4 a4 = *(float4*)&wt[lc][tx * 4];
            float4 b4 = *(float4*)&xt[lc][ty * 4];
            float av[4] = {a4.x, a4.y, a4.z, a4.w};
            float bv[4] = {b4.x, b4.y, b4.z, b4.w};
#pragma unroll
            for (int i = 0; i < 4; ++i)
#pragma unroll
                for (int j = 0; j < 4; ++j) acc[i][j] += av[i] * bv[j];
        }
    }
    int sec = tile_o >> 3, h = tile_o & 7;
    if (sec == 0) {
        unsigned short* dst = qb + (size_t)h * SPAT * 64;
#pragma unroll
        for (int j = 0; j < 4; ++j) {
            int p = p0 + ty * 4 + j;
            ushort4 val = {f2bf(acc[0][j] * QSCALE), f2bf(acc[1][j] * QSCALE),
                           f2bf(acc[2][j] * QSCALE), f2bf(acc[3][j] * QSCALE)};
            *(ushort4*)&dst[(size_t)p * 64 + tx * 4] = val;
        }
    } else if (sec == 1) {
        unsigned short* dst = kb + (size_t)h * TTOKP * 64;
#pragma unroll
        for (int j = 0; j < 4; ++j) {
            int tt = MEMTOK + p0 + ty * 4 + j;
            ushort4 val = {f2bf(acc[0][j]), f2bf(acc[1][j]),
                           f2bf(acc[2][j]), f2bf(acc[3][j])};
            *(ushort4*)&dst[(size_t)tt * 64 + tx * 4] = val;
        }
    } else {  // v: LDS transpose -> [d][t] rows (plain key order)
        unsigned short* vst = (unsigned short*)smem;   // 64 x 68 bf16
        __syncthreads();
#pragma unroll
        for (int i = 0; i < 4; ++i)
#pragma unroll
            for (int j = 0; j < 4; ++j)
                vst[(tx * 4 + i) * 68 + ty * 4 + j] = f2bf(acc[i][j]);
        __syncthreads();
        unsigned short* dst = vtb + (size_t)h * 64 * TTOKP;
        int row = t >> 2;            // d 0..63
        int off = (t & 3) * 16;      // 0,16,32,48
#pragma unroll
        for (int q = 0; q < 4; ++q)  // 8B stores
            *(ushort4*)&dst[(size_t)row * TTOKP + MEMTOK + p0 + off + q * 4] =
                *(ushort4*)&vst[row * 68 + off + q * 4];
    }
}

// ---------------------------------------------------------------------------
// attn_flash: R3-proven computation (S-form, online softmax exp2-domain,
// P roundtrip via wave-private LDS, split-K x2, (m,l) partials), with K/V
// tiles staged once per block into LDS via XOR-swizzled global_load_lds(16B),
// double-buffered, one barrier per tile.
// LDS map: Kbuf[2][64][64], Vbuf[2][64][64] (block b of row r stored at
// b^(r&7)), Ps[4][16][PITCHP].
// ---------------------------------------------------------------------------
__global__ __launch_bounds__(256, 4) void attn_flash(const unsigned short* __restrict__ qb,
                                                     const unsigned short* __restrict__ kb,
                                                     const unsigned short* __restrict__ vtb,
                                                     float* __restrict__ Op,
                                                     float2* __restrict__ Ml) {
    const int h = blockIdx.y, split = blockIdx.z;
    const int p0 = blockIdx.x * 64;
    const int ts = split ? 33 : 0, te = split ? 65 : 33;

    __shared__ __align__(16) unsigned short Kbuf[2 * 4096];
    __shared__ __align__(16) unsigned short Vbuf[2 * 4096];
    __shared__ __align__(16) unsigned short Ps[4 * 16 * PITCHP];

    const int t = threadIdx.x, w = t >> 6, lane = t & 63;
    const int col16 = lane & 15, quad = lane >> 4;
    const int srow = lane >> 3, sblk = lane & 7;

    const unsigned short* kh = kb + (size_t)h * TTOKP * 64;
    const unsigned short* vh = vtb + (size_t)h * 64 * TTOKP;

    // Q A-frags, persistent: row = p0 + w*16 + col16 (per-lane global loads)
    const unsigned short* qrp = qb + ((size_t)h * SPAT + p0 + w * 16 + col16) * 64;
    bf16x8 aq0 = ldb8(qrp + quad * 8);
    bf16x8 aq1 = ldb8(qrp + 32 + quad * 8);

    f32x4 Oa[4];
    float m_i[4], l_i[4];
#pragma unroll
    for (int r = 0; r < 4; ++r) { m_i[r] = -1e30f; l_i[r] = 0.f; }
#pragma unroll
    for (int nt = 0; nt < 4; ++nt) Oa[nt] = (f32x4){0.f, 0.f, 0.f, 0.f};

    unsigned short* pw = &Ps[w * 16 * PITCHP];

    // stage tile into buf: rows r = g*8+srow (g = w, w+4), block sblk holds
    // global block sblk ^ (r&7); LDS dest wave-uniform base + lane*16B.
    auto issue = [&](int tile, int buf) {
#pragma unroll
        for (int gi = 0; gi < 2; ++gi) {
            int g = w + gi * 4;
            int r = g * 8 + srow;
            int xoff = (sblk ^ srow) << 3;
            gload_lds16(kh + (size_t)(tile * 64 + r) * 64 + xoff,
                        &Kbuf[buf * 4096 + g * 512]);
            gload_lds16(vh + (size_t)r * TTOKP + tile * 64 + xoff,
                        &Vbuf[buf * 4096 + g * 512]);
        }
    };

    issue(ts, 0);
    const int N = te - ts;
    for (int i = 0; i < N; ++i) {
        const int tile = ts + i, cur = i & 1;
        __syncthreads();     // drains loads(tile) issued last iter + prev reads
        if (i + 1 < N) issue(tile + 1, cur ^ 1);
        const unsigned short* Kb = &Kbuf[cur * 4096];
        const unsigned short* Vb = &Vbuf[cur * 4096];

        // S = Q K^T: rows (m) = w*16 + quad*4 + r, keys (n) = nt*16 + col16
        f32x4 sv[4];
#pragma unroll
        for (int nt = 0; nt < 4; ++nt) sv[nt] = (f32x4){0.f, 0.f, 0.f, 0.f};
#pragma unroll
        for (int nt = 0; nt < 4; ++nt) {
            int rb = nt * 16 + col16;
            bf16x8 b0 = ldb8(Kb + rb * 64 + (((quad) ^ (rb & 7)) << 3));
            bf16x8 b1 = ldb8(Kb + rb * 64 + (((quad + 4) ^ (rb & 7)) << 3));
            sv[nt] = __builtin_amdgcn_mfma_f32_16x16x32_bf16(aq0, b0, sv[nt], 0, 0, 0);
            sv[nt] = __builtin_amdgcn_mfma_f32_16x16x32_bf16(aq1, b1, sv[nt], 0, 0, 0);
        }
        if (tile == 64) {   // valid keys: nt*16+col16 < 4
#pragma unroll
            for (int nt = 0; nt < 4; ++nt)
#pragma unroll
                for (int r = 0; r < 4; ++r)
                    if (nt * 16 + col16 >= TTOK - 4096) sv[nt][r] = -1e30f;
        }

        // online softmax (exp2 domain); row = quad*4+r, keys across col16 lanes
        float alpha[4];
#pragma unroll
        for (int r = 0; r < 4; ++r) {
            float rm = fmaxf(fmaxf(sv[0][r], sv[1][r]), fmaxf(sv[2][r], sv[3][r]));
            rm = fmaxf(rm, __shfl_xor(rm, 1, 64));
            rm = fmaxf(rm, __shfl_xor(rm, 2, 64));
            rm = fmaxf(rm, __shfl_xor(rm, 4, 64));
            rm = fmaxf(rm, __shfl_xor(rm, 8, 64));
            float mn = fmaxf(m_i[r], rm);
            alpha[r] = __builtin_amdgcn_exp2f(m_i[r] - mn);
            m_i[r] = mn;
            float rs = 0.f;
#pragma unroll
            for (int nt = 0; nt < 4; ++nt) {
                float pv = __builtin_amdgcn_exp2f(sv[nt][r] - mn);
                sv[nt][r] = pv;
                rs += pv;
            }
            rs += __shfl_xor(rs, 1, 64);
            rs += __shfl_xor(rs, 2, 64);
            rs += __shfl_xor(rs, 4, 64);
            rs += __shfl_xor(rs, 8, 64);
            l_i[r] = l_i[r] * alpha[r] + rs;
        }
#pragma unroll
        for (int nt = 0; nt < 4; ++nt) {
            Oa[nt][0] *= alpha[0]; Oa[nt][1] *= alpha[1];
            Oa[nt][2] *= alpha[2]; Oa[nt][3] *= alpha[3];
        }

        // P: C-layout -> wave-private LDS -> A-layout
#pragma unroll
        for (int nt = 0; nt < 4; ++nt)
#pragma unroll
            for (int r = 0; r < 4; ++r)
                pw[(quad * 4 + r) * PITCHP + nt * 16 + col16] = f2bf(sv[nt][r]);

        bf16x8 pa0 = ldb8(&pw[col16 * PITCHP + quad * 8]);
        bf16x8 pa1 = ldb8(&pw[col16 * PITCHP + 32 + quad * 8]);

        // O += P V: B[k=key][n=d] from Vbuf row d = nt*16+col16
#pragma unroll
        for (int nt = 0; nt < 4; ++nt) {
            int rd = nt * 16 + col16;
            bf16x8 v0 = ldb8(Vb + rd * 64 + (((quad) ^ (rd & 7)) << 3));
            bf16x8 v1 = ldb8(Vb + rd * 64 + (((quad + 4) ^ (rd & 7)) << 3));
            Oa[nt] = __builtin_amdgcn_mfma_f32_16x16x32_bf16(pa0, v0, Oa[nt], 0, 0, 0);
            Oa[nt] = __builtin_amdgcn_mfma_f32_16x16x32_bf16(pa1, v1, Oa[nt], 0, 0, 0);
        }
    }

    // epilogue: undivided partials + (m,l)
    size_t rowbase = ((size_t)(split * HEADS_N + h) * SPAT + p0 + w * 16);
#pragma unroll
    for (int nt = 0; nt < 4; ++nt)
#pragma unroll
        for (int r = 0; r < 4; ++r)
            Op[(rowbase + quad * 4 + r) * 64 + nt * 16 + col16] = Oa[nt][r];
    if (col16 == 0) {
#pragma unroll
        for (int r = 0; r < 4; ++r)
            Ml[rowbase + quad * 4 + r] = make_float2(m_i[r], l_i[r]);
    }
}

// ---------------------------------------------------------------------------
// merge: ob[h][p][d] = (w0*O0 + w1*O1) / (w0*l0 + w1*l1), wi = exp2(mi - m)
// ---------------------------------------------------------------------------
__global__ __launch_bounds__(256) void merge_kernel(const float* __restrict__ Op,
                                                    const float2* __restrict__ Ml,
                                                    float* __restrict__ ob) {
    int g = blockIdx.x * 256 + threadIdx.x;   // f32x4 groups
    int row = g >> 4;
    float4 o0 = ((const float4*)Op)[g];
    float4 o1 = ((const float4*)(Op + (size_t)HEADS_N * SPAT * 64))[g];
    float2 ml0 = Ml[row];
    float2 ml1 = Ml[row + HEADS_N * SPAT];
    float m = fmaxf(ml0.x, ml1.x);
    float w0 = __builtin_amdgcn_exp2f(ml0.x - m);
    float w1 = __builtin_amdgcn_exp2f(ml1.x - m);
    float inv = 1.0f / (w0 * ml0.y + w1 * ml1.y);
    float a0 = w0 * inv, a1 = w1 * inv;
    float4 o = {o0.x * a0 + o1.x * a1, o0.y * a0 + o1.y * a1,
                o0.z * a0 + o1.z * a1, o0.w * a0 + o1.w * a1};
    ((float4*)ob)[g] = o;
}

// ---------------------------------------------------------------------------
// out_gemm (fp32): out[oc,p] = sum_{h,d} w_out[oc,h*64+d] * ob[h][p][d]
// ---------------------------------------------------------------------------
__global__ __launch_bounds__(256) void out_gemm(const float* __restrict__ w,
                                                const float* __restrict__ ob,
                                                float* __restrict__ out) {
    int p0 = blockIdx.x * 64;
    int o0 = blockIdx.y * 64;
    __shared__ float at[16][68];
    __shared__ float bt[16][68];
    int t = threadIdx.x;
    int tx = t & 15, ty = t >> 4;
    float acc[4][4];
#pragma unroll
    for (int i = 0; i < 4; ++i)
#pragma unroll
        for (int j = 0; j < 4; ++j) acc[i][j] = 0.f;

    for (int c0 = 0; c0 < HID; c0 += 16) {
        int hh = c0 >> 6;
        int d0 = c0 & 63;
        __syncthreads();
        {
            int lo = t >> 2, lc4 = (t & 3) * 4;
            float4 wv = *(const float4*)&w[(size_t)(o0 + lo) * HID + c0 + lc4];
            at[lc4 + 0][lo] = wv.x; at[lc4 + 1][lo] = wv.y;
            at[lc4 + 2][lo] = wv.z; at[lc4 + 3][lo] = wv.w;
        }
        {
            int lp = t >> 2, ld4 = (t & 3) * 4;
            float4 bv = *(const float4*)&ob[(size_t)hh * SPAT * 64 + (size_t)(p0 + lp) * 64 + d0 + ld4];
            bt[ld4 + 0][lp] = bv.x; bt[ld4 + 1][lp] = bv.y;
            bt[ld4 + 2][lp] = bv.z; bt[ld4 + 3][lp] = bv.w;
        }
        __syncthreads();
#pragma unroll
        for (int lc = 0; lc < 16; ++lc) {
            float4 a4 = *(float4*)&at[lc][tx * 4];
            float4 b4 = *(float4*)&bt[lc][ty * 4];
            float av[4] = {a4.x, a4.y, a4.z, a4.w};
            float bv[4] = {b4.x, b4.y, b4.z, b4.w};
#pragma unroll
            for (int i = 0; i < 4; ++i)
#pragma unroll
                for (int j = 0; j < 4; ++j) acc[i][j] += av[i] * bv[j];
        }
    }
#pragma unroll
    for (int i = 0; i < 4; ++i) {
        float4 val = {acc[i][0], acc[i][1], acc[i][2], acc[i][3]};
        *(float4*)&out[(size_t)(o0 + tx * 4 + i) * SPAT + p0 + ty * 4] = val;
    }
}

// ---------------------------------------------------------------------------
// Launch
// ---------------------------------------------------------------------------
extern "C" void kernel_launch(void* const* d_in, const int* in_sizes, int n_in,
                              void* d_out, int out_size, void* d_ws, size_t ws_size,
                              hipStream_t stream) {
    const float* x      = (const float*)d_in[0];
    const float* gamma  = (const float*)d_in[1];
    const float* mem_kv = (const float*)d_in[2];
    const float* w_qkv  = (const float*)d_in[3];
    const float* w_out  = (const float*)d_in[4];
    float* out = (float*)d_out;

    char* p = (char*)d_ws;
    float* invn = (float*)p;                 p += (size_t)SPAT * 4;
    unsigned short* qb  = (unsigned short*)p; p += (size_t)HEADS_N * SPAT * 64 * 2;
    unsigned short* kb  = (unsigned short*)p; p += (size_t)HEADS_N * TTOKP * 64 * 2;
    unsigned short* vtb = (unsigned short*)p; p += (size_t)HEADS_N * 64 * TTOKP * 2;
    float* ob = (float*)p;                   p += (size_t)HEADS_N * SPAT * 64 * 4;
    float* Op = (float*)p;                   p += (size_t)2 * HEADS_N * SPAT * 64 * 4;
    float2* Ml = (float2*)p;                 p += (size_t)2 * HEADS_N * SPAT * 8;

    rms_inv<<<dim3(64), 256, 0, stream>>>(x, invn);
    fixup_kernel<<<dim3(256), 256, 0, stream>>>(mem_kv, kb, vtb);
    qkv_gemm<<<dim3(64, 24), 256, 0, stream>>>(w_qkv, x, invn, gamma, qb, kb, vtb);
    attn_flash<<<dim3(64, HEADS_N, 2), 256, 0, stream>>>(qb, kb, vtb, Op, Ml);
    merge_kernel<<<dim3(2048), 256, 0, stream>>>(Op, Ml, ob);
    out_gemm<<<dim3(64, 4), 256, 0, stream>>>(w_out, ob, out);
}